// Round 9
// baseline (375.738 us; speedup 1.0000x reference)
//
#include <hip/hip_runtime.h>

#define HID 128
#define CLS 10

typedef short short8 __attribute__((ext_vector_type(8)));
typedef float f32x4 __attribute__((ext_vector_type(4)));

// float -> bf16 round-to-nearest-even
__device__ __forceinline__ unsigned short f2bf(float f) {
  union { float f; unsigned u; } v; v.f = f;
  unsigned u = v.u;
  return (unsigned short)((u + 0x7FFFu + ((u >> 16) & 1u)) >> 16);
}
__device__ __forceinline__ float bf_lo(unsigned p) { return __uint_as_float(p << 16); }
__device__ __forceinline__ float bf_hi(unsigned p) { return __uint_as_float(p & 0xFFFF0000u); }

// ---------------- setup: zero degi + build Wt (fused, grid-partitioned) ----------------

__global__ __launch_bounds__(256) void zero_wt(int* __restrict__ degi, int n, int nbN,
                                               const float* __restrict__ W1,
                                               const float* __restrict__ W2,
                                               const float* __restrict__ W3,
                                               unsigned short* __restrict__ Wt) {
  int b = blockIdx.x;
  if (b < nbN) {
    int i = b * 256 + threadIdx.x;
    if (i < n) degi[i] = 0;
    return;
  }
  int wb = b - nbN;                  // 0..47
  int mat = wb >> 4;                 // 0..2
  int part = wb & 15;                // 0..15
  const float* W = (mat == 0) ? W1 : (mat == 1) ? W2 : W3;
  unsigned short* o = Wt + (size_t)mat * HID * HID;
  int base = part * (HID * HID / 16);
  for (int r = 0; r < HID * HID / 16; r += 256) {
    int idx = base + r + threadIdx.x;
    int k = idx >> 7, nn = idx & 127;
    o[nn * HID + k] = f2bf(W[idx]);   // Wt[n][k] = W[k][n]
  }
}

__global__ __launch_bounds__(256) void degree_k(const int* __restrict__ dst,
                                                int* __restrict__ degi, int E) {
  int e = blockIdx.x * 256 + threadIdx.x;
  if (e < E) atomicAdd(&degi[dst[e]], 1);
}

// scan of degrees + dinv + zeroing of fillc/pooled (both consumed later)
__global__ __launch_bounds__(256) void scan_chunk(const int* __restrict__ degi,
                                                  int* __restrict__ row_ptr,
                                                  int* __restrict__ blockSums,
                                                  float* __restrict__ dinv,
                                                  int* __restrict__ fillc,
                                                  float* __restrict__ pooled,
                                                  int n, int gh) {
  __shared__ int sd[256];
  int t = threadIdx.x;
  int i = blockIdx.x * 256 + t;
  int v = (i < n) ? degi[i] : 0;
  if (i < n) { dinv[i] = rsqrtf((float)v + 1.0f); fillc[i] = 0; }  // +1 self-loop
  if (i < gh) pooled[i] = 0.f;
  sd[t] = v;
  for (int off = 1; off < 256; off <<= 1) {
    __syncthreads();
    int x = (t >= off) ? sd[t - off] : 0;
    __syncthreads();
    sd[t] += x;
  }
  if (i < n) row_ptr[i] = sd[t] - v;
  if (t == 255) blockSums[blockIdx.x] = sd[255];
}

// every block redundantly scans blockSums (nb<=256) in LDS, then applies its offset
__global__ __launch_bounds__(256) void scan_addtop(int* __restrict__ row_ptr,
                                                   const int* __restrict__ blockSums,
                                                   int nb, int n, int E) {
  __shared__ int sv[256];
  __shared__ int sd[256];
  int t = threadIdx.x;
  int v = (t < nb) ? blockSums[t] : 0;
  sv[t] = v;
  sd[t] = v;
  for (int off = 1; off < 256; off <<= 1) {
    __syncthreads();
    int x = (t >= off) ? sd[t - off] : 0;
    __syncthreads();
    sd[t] += x;
  }
  __syncthreads();
  int myoff = sd[blockIdx.x] - sv[blockIdx.x];  // exclusive prefix for this block
  int i = blockIdx.x * 256 + t;
  if (i < n) row_ptr[i] += myoff;
  if (i == 0) row_ptr[n] = E;
}

__global__ __launch_bounds__(256) void csr_fill(const int* __restrict__ src,
                                                const int* __restrict__ dst,
                                                const int* __restrict__ row_ptr,
                                                int* __restrict__ fillc,
                                                int* __restrict__ col_src, int E) {
  int e = blockIdx.x * 256 + threadIdx.x;
  if (e >= E) return;
  int s = src[e], d = dst[e];
  int slot = atomicAdd(&fillc[d], 1);
  col_src[row_ptr[d] + slot] = s;
}

// ---------------- MFMA bf16 GEMM: Tb[r,:] = bf16( dinv[r] * (A[r,:] @ W) ) ----------------
// Layer 1 only (fp32 x input, converted in-register). 128 rows/block.

#define WTP 136  // 128 + 8 pad

__global__ __launch_bounds__(256) void gemm_mfma(const float* __restrict__ A,
                                                 const unsigned short* __restrict__ Wt,  // bf16 [n][k]
                                                 const float* __restrict__ dinv,
                                                 unsigned short* __restrict__ Tb,  // bf16 [n][128]
                                                 int nrows) {
  __shared__ unsigned short sW[HID][WTP];
  int tid = threadIdx.x;
  int wave = tid >> 6, lane = tid & 63;
  int m_lo = lane & 15, quad = lane >> 4;
  int row0 = blockIdx.x * 128;
  int rbase = row0 + wave * 32;

  uint4 araw[2][4];
#pragma unroll
  for (int tr = 0; tr < 2; ++tr) {
    int grow = rbase + tr * 16 + m_lo;
    int gr = (grow < nrows) ? grow : (nrows - 1);  // clamp: stores guarded later
    const float* Arow = A + (size_t)gr * HID;
#pragma unroll
    for (int kb = 0; kb < 4; ++kb) {
      float4 f0 = *(const float4*)&Arow[kb * 32 + quad * 8];
      float4 f1 = *(const float4*)&Arow[kb * 32 + quad * 8 + 4];
      uint4 u;
      u.x = (unsigned)f2bf(f0.x) | ((unsigned)f2bf(f0.y) << 16);
      u.y = (unsigned)f2bf(f0.z) | ((unsigned)f2bf(f0.w) << 16);
      u.z = (unsigned)f2bf(f1.x) | ((unsigned)f2bf(f1.y) << 16);
      u.w = (unsigned)f2bf(f1.z) | ((unsigned)f2bf(f1.w) << 16);
      araw[tr][kb] = u;
    }
  }

  const uint4* Wt4 = (const uint4*)Wt;
#pragma unroll
  for (int i = 0; i < 8; ++i) {
    int idx = i * 256 + tid;
    *(uint4*)&sW[idx >> 4][(idx & 15) * 8] = Wt4[idx];
  }
  __syncthreads();

  f32x4 acc[2][8];
#pragma unroll
  for (int tr = 0; tr < 2; ++tr)
#pragma unroll
    for (int tc = 0; tc < 8; ++tc) acc[tr][tc] = (f32x4)(0.f);

#pragma unroll
  for (int kb = 0; kb < 4; ++kb) {
    short8 b[8];
#pragma unroll
    for (int tc = 0; tc < 8; ++tc) {
      union { uint4 u; short8 s; } cv;
      cv.u = *(const uint4*)&sW[tc * 16 + m_lo][kb * 32 + quad * 8];
      b[tc] = cv.s;
    }
#pragma unroll
    for (int tr = 0; tr < 2; ++tr) {
      union { uint4 u; short8 s; } av;
      av.u = araw[tr][kb];
#pragma unroll
      for (int tc = 0; tc < 8; ++tc)
        acc[tr][tc] = __builtin_amdgcn_mfma_f32_16x16x32_bf16(av.s, b[tc], acc[tr][tc], 0, 0, 0);
    }
  }

#pragma unroll
  for (int tr = 0; tr < 2; ++tr) {
#pragma unroll
    for (int r = 0; r < 4; ++r) {
      int grow = rbase + tr * 16 + quad * 4 + r;
      if (grow < nrows) {
        float s = dinv[grow];
        unsigned short* orow = &Tb[(size_t)grow * HID];
#pragma unroll
        for (int tc = 0; tc < 8; ++tc)
          orow[tc * 16 + m_lo] = f2bf(s * acc[tr][tc][r]);
      }
    }
  }
}

// ---------------- fused: H_l = relu(b + dinv*(T_in[self]+sum T_in[src])); T_out = dinv*(H_l @ W) ----------------
// 64 rows/block, 4 waves: each wave aggregates 16 nodes into LDS (bf16x2 packed),
// then MFMAs its own 16-row tile against W (staged in LDS). One barrier.

#define FTM 64
#define SHP 68  // 64 + 4 pad dwords: phase-2 reads are 2-way (free) instead of 16-way

__global__ __launch_bounds__(256) void fused_ag(const unsigned* __restrict__ Tin,  // bf16x2 [n][64]
                                                const float* __restrict__ dinv,
                                                const int* __restrict__ row_ptr,
                                                const int* __restrict__ col_src,
                                                const float* __restrict__ bias,
                                                const unsigned short* __restrict__ Wt,
                                                unsigned short* __restrict__ Tout,  // bf16 [n][128]
                                                int nrows) {
  __shared__ unsigned sH[FTM][SHP];        // 17.4 KB
  __shared__ unsigned short sW[HID][WTP];  // 34.8 KB
  int tid = threadIdx.x;
  int wave = tid >> 6, lane = tid & 63;
  int row0 = blockIdx.x * FTM;

  // stage W (issues early; waits absorbed by gather phase)
  const uint4* Wt4 = (const uint4*)Wt;
#pragma unroll
  for (int i = 0; i < 8; ++i) {
    int idx = i * 256 + tid;
    *(uint4*)&sW[idx >> 4][(idx & 15) * 8] = Wt4[idx];
  }

  // phase 1: each wave aggregates 16 nodes; lane owns col pair 2*lane
  int c = lane * 2;
  for (int i = 0; i < 16; ++i) {
    int node = row0 + wave * 16 + i;
    unsigned outp = 0u;
    if (node < nrows) {
      unsigned v0 = Tin[(size_t)node * 64 + lane];
      float ax = bf_lo(v0), ay = bf_hi(v0);
      int j = row_ptr[node], end = row_ptr[node + 1];
      for (; j + 8 <= end; j += 8) {
        int idx[8];
#pragma unroll
        for (int u = 0; u < 8; ++u) idx[u] = col_src[j + u];
        unsigned v[8];
#pragma unroll
        for (int u = 0; u < 8; ++u) v[u] = Tin[(size_t)idx[u] * 64 + lane];
#pragma unroll
        for (int u = 0; u < 8; ++u) { ax += bf_lo(v[u]); ay += bf_hi(v[u]); }
      }
      if (j + 4 <= end) {
        int idx[4];
#pragma unroll
        for (int u = 0; u < 4; ++u) idx[u] = col_src[j + u];
        unsigned v[4];
#pragma unroll
        for (int u = 0; u < 4; ++u) v[u] = Tin[(size_t)idx[u] * 64 + lane];
#pragma unroll
        for (int u = 0; u < 4; ++u) { ax += bf_lo(v[u]); ay += bf_hi(v[u]); }
        j += 4;
      }
      for (; j < end; ++j) {
        unsigned v = Tin[(size_t)col_src[j] * 64 + lane];
        ax += bf_lo(v);
        ay += bf_hi(v);
      }
      float di = dinv[node];
      ax = fmaxf(di * ax + bias[c], 0.f);
      ay = fmaxf(di * ay + bias[c + 1], 0.f);
      outp = (unsigned)f2bf(ax) | ((unsigned)f2bf(ay) << 16);
    }
    sH[wave * 16 + i][lane] = outp;
  }
  __syncthreads();

  // phase 2: wave computes its own 16 rows x 128 cols
  int m_lo = lane & 15, quad = lane >> 4;
  f32x4 acc[8];
#pragma unroll
  for (int tc = 0; tc < 8; ++tc) acc[tc] = (f32x4)(0.f);

#pragma unroll
  for (int kb = 0; kb < 4; ++kb) {
    union { uint4 u; short8 s; } av;
    av.u = *(const uint4*)&sH[wave * 16 + m_lo][kb * 16 + quad * 4];
#pragma unroll
    for (int tc = 0; tc < 8; ++tc) {
      union { uint4 u; short8 s; } bv;
      bv.u = *(const uint4*)&sW[tc * 16 + m_lo][kb * 32 + quad * 8];
      acc[tc] = __builtin_amdgcn_mfma_f32_16x16x32_bf16(av.s, bv.s, acc[tc], 0, 0, 0);
    }
  }

#pragma unroll
  for (int r = 0; r < 4; ++r) {
    int grow = row0 + wave * 16 + quad * 4 + r;
    if (grow < nrows) {
      float s = dinv[grow];
      unsigned short* orow = &Tout[(size_t)grow * HID];
#pragma unroll
      for (int tc = 0; tc < 8; ++tc)
        orow[tc * 16 + m_lo] = f2bf(s * acc[tc][r]);
    }
  }
}

// ---------------- aggregate (layer 3 only): Hb = bf16(relu(b + dinv*(T[self]+sum T[src]))) ----------------

__global__ __launch_bounds__(256) void aggregate(const unsigned* __restrict__ Tb2,
                                                 const float* __restrict__ dinv,
                                                 const int* __restrict__ row_ptr,
                                                 const int* __restrict__ col_src,
                                                 const float* __restrict__ bias,
                                                 unsigned* __restrict__ Hb, int n) {
  int node = (blockIdx.x * 256 + threadIdx.x) >> 6;
  if (node >= n) return;
  int lane = threadIdx.x & 63;
  int c = lane * 2;
  unsigned v0 = Tb2[(size_t)node * 64 + lane];
  float ax = bf_lo(v0);
  float ay = bf_hi(v0);
  int j = row_ptr[node], end = row_ptr[node + 1];
  for (; j + 8 <= end; j += 8) {
    int idx[8];
#pragma unroll
    for (int u = 0; u < 8; ++u) idx[u] = col_src[j + u];
    unsigned v[8];
#pragma unroll
    for (int u = 0; u < 8; ++u) v[u] = Tb2[(size_t)idx[u] * 64 + lane];
#pragma unroll
    for (int u = 0; u < 8; ++u) { ax += bf_lo(v[u]); ay += bf_hi(v[u]); }
  }
  if (j + 4 <= end) {
    int idx[4];
#pragma unroll
    for (int u = 0; u < 4; ++u) idx[u] = col_src[j + u];
    unsigned v[4];
#pragma unroll
    for (int u = 0; u < 4; ++u) v[u] = Tb2[(size_t)idx[u] * 64 + lane];
#pragma unroll
    for (int u = 0; u < 4; ++u) { ax += bf_lo(v[u]); ay += bf_hi(v[u]); }
    j += 4;
  }
  for (; j < end; ++j) {
    unsigned v = Tb2[(size_t)col_src[j] * 64 + lane];
    ax += bf_lo(v);
    ay += bf_hi(v);
  }
  float di = dinv[node];
  ax = fmaxf(di * ax + bias[c], 0.f);
  ay = fmaxf(di * ay + bias[c + 1], 0.f);
  Hb[(size_t)node * 64 + lane] = (unsigned)f2bf(ax) | ((unsigned)f2bf(ay) << 16);
}

// ---------------- pooling (reads packed bf16 H); 16 nodes per block ----------------

__global__ __launch_bounds__(64) void pool_partial(const unsigned* __restrict__ Hb,
                                                   const int* __restrict__ batch,
                                                   float* __restrict__ pooled, int n) {
  int t = threadIdx.x;  // col pair
  int s = blockIdx.x * 16;
  if (s >= n) return;
  int e = min(s + 16, n);
  int g = batch[s];
  float ax = 0.f, ay = 0.f;
  for (int i = s; i < e; ++i) {
    int bi = batch[i];
    if (bi != g) {
      atomicAdd(&pooled[g * HID + 2 * t], ax);
      atomicAdd(&pooled[g * HID + 2 * t + 1], ay);
      ax = ay = 0.f;
      g = bi;
    }
    unsigned v = Hb[(size_t)i * 64 + t];
    ax += bf_lo(v);
    ay += bf_hi(v);
  }
  atomicAdd(&pooled[g * HID + 2 * t], ax);
  atomicAdd(&pooled[g * HID + 2 * t + 1], ay);
}

__global__ __launch_bounds__(128) void classify_k(const float* __restrict__ pooled,
                                                  const int* __restrict__ batch,
                                                  const float* __restrict__ Wl,
                                                  const float* __restrict__ bl,
                                                  float* __restrict__ out, int n) {
  int g = blockIdx.x;
  int t = threadIdx.x;
  int lo = 0, hi = n;
  while (lo < hi) { int mid = (lo + hi) >> 1; if (batch[mid] < g) lo = mid + 1; else hi = mid; }
  int s = lo;
  hi = n;
  while (lo < hi) { int mid = (lo + hi) >> 1; if (batch[mid] < g + 1) lo = mid + 1; else hi = mid; }
  float c = fmaxf((float)(lo - s), 1.0f);
  __shared__ float p[HID];
  p[t] = pooled[g * HID + t] / c;
  __syncthreads();
  if (t < CLS) {
    float o = bl[t];
    for (int j = 0; j < HID; ++j) o += p[j] * Wl[j * CLS + t];
    out[g * CLS + t] = o;
  }
}

// ---------------- launch ----------------

extern "C" void kernel_launch(void* const* d_in, const int* in_sizes, int n_in,
                              void* d_out, int out_size, void* d_ws, size_t ws_size,
                              hipStream_t stream) {
  const float* x  = (const float*)d_in[0];
  const float* W1 = (const float*)d_in[1];
  const float* b1 = (const float*)d_in[2];
  const float* W2 = (const float*)d_in[3];
  const float* b2 = (const float*)d_in[4];
  const float* W3 = (const float*)d_in[5];
  const float* b3 = (const float*)d_in[6];
  const float* Wl = (const float*)d_in[7];
  const float* bl = (const float*)d_in[8];
  const int* edge_index = (const int*)d_in[9];
  const int* batch = (const int*)d_in[10];

  const int N = in_sizes[10];
  const int E = in_sizes[9] / 2;
  const int G = out_size / CLS;
  const int* src = edge_index;
  const int* dst = edge_index + E;

  uintptr_t p = (uintptr_t)d_ws;
  auto take = [&](size_t bytes) -> void* {
    void* r = (void*)p;
    p += (bytes + 255) & ~(size_t)255;
    return r;
  };
  int*      degi      = (int*)take((size_t)N * 4);
  int*      fillc     = (int*)take((size_t)N * 4);
  int*      row_ptr   = (int*)take((size_t)(N + 1) * 4);
  int*      blockSums = (int*)take(256 * 4);
  float*    dinv      = (float*)take((size_t)N * 4);
  int*      col_src   = (int*)take((size_t)E * 4);
  unsigned short* WtA = (unsigned short*)take((size_t)3 * HID * HID * 2);
  unsigned short* bufTa = (unsigned short*)take((size_t)N * HID * 2);
  unsigned short* bufTb = (unsigned short*)take((size_t)N * HID * 2);
  unsigned* bufHb     = (unsigned*)take((size_t)N * 64 * 4);
  float*    pooled    = (float*)take((size_t)G * HID * 4);

  int nbN = (N + 255) / 256;
  int nbE = (E + 255) / 256;

  zero_wt<<<nbN + 48, 256, 0, stream>>>(degi, N, nbN, W1, W2, W3, WtA);
  degree_k<<<nbE, 256, 0, stream>>>(dst, degi, E);
  scan_chunk<<<nbN, 256, 0, stream>>>(degi, row_ptr, blockSums, dinv, fillc, pooled, N, G * HID);
  scan_addtop<<<nbN, 256, 0, stream>>>(row_ptr, blockSums, nbN, N, E);
  csr_fill<<<nbE, 256, 0, stream>>>(src, dst, row_ptr, fillc, col_src, E);

  int gemmBlocks = (N + 127) / 128;
  int fusedBlocks = (N + FTM - 1) / FTM;
  int aggBlocks = (N * 64 + 255) / 256;

  gemm_mfma<<<gemmBlocks, 256, 0, stream>>>(x, WtA, dinv, bufTa, N);
  fused_ag<<<fusedBlocks, 256, 0, stream>>>((unsigned*)bufTa, dinv, row_ptr, col_src, b1,
                                            WtA + (size_t)HID * HID, bufTb, N);
  fused_ag<<<fusedBlocks, 256, 0, stream>>>((unsigned*)bufTb, dinv, row_ptr, col_src, b2,
                                            WtA + (size_t)2 * HID * HID, bufTa, N);
  aggregate<<<aggBlocks, 256, 0, stream>>>((unsigned*)bufTa, dinv, row_ptr, col_src, b3, bufHb, N);

  pool_partial<<<(N + 15) / 16, 64, 0, stream>>>(bufHb, batch, pooled, N);
  classify_k<<<G, 128, 0, stream>>>(pooled, batch, Wl, bl, (float*)d_out, N);
}

// Round 10
// 289.609 us; speedup vs baseline: 1.2974x; 1.2974x over previous
//
#include <hip/hip_runtime.h>

#define HID 128
#define CLS 10

typedef short short8 __attribute__((ext_vector_type(8)));
typedef float f32x4 __attribute__((ext_vector_type(4)));

// float -> bf16 round-to-nearest-even
__device__ __forceinline__ unsigned short f2bf(float f) {
  union { float f; unsigned u; } v; v.f = f;
  unsigned u = v.u;
  return (unsigned short)((u + 0x7FFFu + ((u >> 16) & 1u)) >> 16);
}
__device__ __forceinline__ float bf_lo(unsigned p) { return __uint_as_float(p << 16); }
__device__ __forceinline__ float bf_hi(unsigned p) { return __uint_as_float(p & 0xFFFF0000u); }

// ---------------- setup: zero degi + build Wt (fused, grid-partitioned) ----------------

__global__ __launch_bounds__(256) void zero_wt(int* __restrict__ degi, int n, int nbN,
                                               const float* __restrict__ W1,
                                               const float* __restrict__ W2,
                                               const float* __restrict__ W3,
                                               unsigned short* __restrict__ Wt) {
  int b = blockIdx.x;
  if (b < nbN) {
    int i = b * 256 + threadIdx.x;
    if (i < n) degi[i] = 0;
    return;
  }
  int wb = b - nbN;                  // 0..47
  int mat = wb >> 4;                 // 0..2
  int part = wb & 15;                // 0..15
  const float* W = (mat == 0) ? W1 : (mat == 1) ? W2 : W3;
  unsigned short* o = Wt + (size_t)mat * HID * HID;
  int base = part * (HID * HID / 16);
  for (int r = 0; r < HID * HID / 16; r += 256) {
    int idx = base + r + threadIdx.x;
    int k = idx >> 7, nn = idx & 127;
    o[nn * HID + k] = f2bf(W[idx]);   // Wt[n][k] = W[k][n]
  }
}

__global__ __launch_bounds__(256) void degree_k(const int* __restrict__ dst,
                                                int* __restrict__ degi, int E) {
  int e = blockIdx.x * 256 + threadIdx.x;
  if (e < E) atomicAdd(&degi[dst[e]], 1);
}

// scan of degrees + dinv + zeroing of fillc/pooled (both consumed later)
__global__ __launch_bounds__(256) void scan_chunk(const int* __restrict__ degi,
                                                  int* __restrict__ row_ptr,
                                                  int* __restrict__ blockSums,
                                                  float* __restrict__ dinv,
                                                  int* __restrict__ fillc,
                                                  float* __restrict__ pooled,
                                                  int n, int gh) {
  __shared__ int sd[256];
  int t = threadIdx.x;
  int i = blockIdx.x * 256 + t;
  int v = (i < n) ? degi[i] : 0;
  if (i < n) { dinv[i] = rsqrtf((float)v + 1.0f); fillc[i] = 0; }  // +1 self-loop
  if (i < gh) pooled[i] = 0.f;
  sd[t] = v;
  for (int off = 1; off < 256; off <<= 1) {
    __syncthreads();
    int x = (t >= off) ? sd[t - off] : 0;
    __syncthreads();
    sd[t] += x;
  }
  if (i < n) row_ptr[i] = sd[t] - v;
  if (t == 255) blockSums[blockIdx.x] = sd[255];
}

// every block redundantly scans blockSums (nb<=256) in LDS, then applies its offset
__global__ __launch_bounds__(256) void scan_addtop(int* __restrict__ row_ptr,
                                                   const int* __restrict__ blockSums,
                                                   int nb, int n, int E) {
  __shared__ int sv[256];
  __shared__ int sd[256];
  int t = threadIdx.x;
  int v = (t < nb) ? blockSums[t] : 0;
  sv[t] = v;
  sd[t] = v;
  for (int off = 1; off < 256; off <<= 1) {
    __syncthreads();
    int x = (t >= off) ? sd[t - off] : 0;
    __syncthreads();
    sd[t] += x;
  }
  __syncthreads();
  int myoff = sd[blockIdx.x] - sv[blockIdx.x];  // exclusive prefix for this block
  int i = blockIdx.x * 256 + t;
  if (i < n) row_ptr[i] += myoff;
  if (i == 0) row_ptr[n] = E;
}

__global__ __launch_bounds__(256) void csr_fill(const int* __restrict__ src,
                                                const int* __restrict__ dst,
                                                const int* __restrict__ row_ptr,
                                                int* __restrict__ fillc,
                                                int* __restrict__ col_src, int E) {
  int e = blockIdx.x * 256 + threadIdx.x;
  if (e >= E) return;
  int s = src[e], d = dst[e];
  int slot = atomicAdd(&fillc[d], 1);
  col_src[row_ptr[d] + slot] = s;
}

// ---------------- MFMA bf16 GEMM: Tb[r,:] = bf16( dinv[r] * (A[r,:] @ W) ) ----------------
// Block = 4 waves x 32 rows = 128 rows. W staged in LDS; A fragments direct
// global->VGPR. a_fp32=1: layer 1 reads fp32 x, converts in-register.

#define WTP 136  // 128 + 8 pad

__global__ __launch_bounds__(256) void gemm_mfma(const void* __restrict__ Aptr,
                                                 int a_fp32,
                                                 const unsigned short* __restrict__ Wt,  // bf16 [n][k]
                                                 const float* __restrict__ dinv,
                                                 unsigned short* __restrict__ Tb,  // bf16 [n][128]
                                                 int nrows) {
  __shared__ unsigned short sW[HID][WTP];
  int tid = threadIdx.x;
  int wave = tid >> 6, lane = tid & 63;
  int m_lo = lane & 15, quad = lane >> 4;
  int row0 = blockIdx.x * 128;
  int rbase = row0 + wave * 32;

  uint4 araw[2][4];
#pragma unroll
  for (int tr = 0; tr < 2; ++tr) {
    int grow = rbase + tr * 16 + m_lo;
    int gr = (grow < nrows) ? grow : (nrows - 1);  // clamp: stores guarded later
    if (a_fp32) {
      const float* Arow = (const float*)Aptr + (size_t)gr * HID;
#pragma unroll
      for (int kb = 0; kb < 4; ++kb) {
        float4 f0 = *(const float4*)&Arow[kb * 32 + quad * 8];
        float4 f1 = *(const float4*)&Arow[kb * 32 + quad * 8 + 4];
        uint4 u;
        u.x = (unsigned)f2bf(f0.x) | ((unsigned)f2bf(f0.y) << 16);
        u.y = (unsigned)f2bf(f0.z) | ((unsigned)f2bf(f0.w) << 16);
        u.z = (unsigned)f2bf(f1.x) | ((unsigned)f2bf(f1.y) << 16);
        u.w = (unsigned)f2bf(f1.z) | ((unsigned)f2bf(f1.w) << 16);
        araw[tr][kb] = u;
      }
    } else {
      const uint4* Arow = (const uint4*)((const unsigned*)Aptr + (size_t)gr * 64);
#pragma unroll
      for (int kb = 0; kb < 4; ++kb) araw[tr][kb] = Arow[kb * 4 + quad];
    }
  }

  const uint4* Wt4 = (const uint4*)Wt;
#pragma unroll
  for (int i = 0; i < 8; ++i) {
    int idx = i * 256 + tid;
    *(uint4*)&sW[idx >> 4][(idx & 15) * 8] = Wt4[idx];
  }
  __syncthreads();

  f32x4 acc[2][8];
#pragma unroll
  for (int tr = 0; tr < 2; ++tr)
#pragma unroll
    for (int tc = 0; tc < 8; ++tc) acc[tr][tc] = (f32x4)(0.f);

#pragma unroll
  for (int kb = 0; kb < 4; ++kb) {
    short8 b[8];
#pragma unroll
    for (int tc = 0; tc < 8; ++tc) {
      union { uint4 u; short8 s; } cv;
      cv.u = *(const uint4*)&sW[tc * 16 + m_lo][kb * 32 + quad * 8];
      b[tc] = cv.s;
    }
#pragma unroll
    for (int tr = 0; tr < 2; ++tr) {
      union { uint4 u; short8 s; } av;
      av.u = araw[tr][kb];
#pragma unroll
      for (int tc = 0; tc < 8; ++tc)
        acc[tr][tc] = __builtin_amdgcn_mfma_f32_16x16x32_bf16(av.s, b[tc], acc[tr][tc], 0, 0, 0);
    }
  }

#pragma unroll
  for (int tr = 0; tr < 2; ++tr) {
#pragma unroll
    for (int r = 0; r < 4; ++r) {
      int grow = rbase + tr * 16 + quad * 4 + r;
      if (grow < nrows) {
        float s = dinv[grow];
        unsigned short* orow = &Tb[(size_t)grow * HID];
#pragma unroll
        for (int tc = 0; tc < 8; ++tc)
          orow[tc * 16 + m_lo] = f2bf(s * acc[tr][tc][r]);
      }
    }
  }
}

// ---------------- aggregate: Hb[d] = bf16( relu(b + dinv[d]*(Tb[d] + sum_e Tb[src_e])) ) ----------------
// TWO nodes per wave: half-wave (32 lanes x 8 B) covers one 256 B row, so each
// 8-deep unrolled load step keeps 16 rows in flight per wave (2x MLP of r8),
// at unchanged occupancy. Per-column summation order identical to r8.

__global__ __launch_bounds__(256) void aggregate(const unsigned* __restrict__ Tb2,
                                                 const float* __restrict__ dinv,
                                                 const int* __restrict__ row_ptr,
                                                 const int* __restrict__ col_src,
                                                 const float* __restrict__ bias,
                                                 unsigned* __restrict__ Hb, int n) {
  int w = (blockIdx.x * 256 + threadIdx.x) >> 6;  // wave id
  int lane = threadIdx.x & 63;
  int half = lane >> 5;
  int l2 = lane & 31;
  int node = w * 2 + half;
  if (node >= n) return;

  uint2 sv = *(const uint2*)&Tb2[(size_t)node * 64 + l2 * 2];
  float a0 = bf_lo(sv.x), a1 = bf_hi(sv.x), a2 = bf_lo(sv.y), a3 = bf_hi(sv.y);
  int j = row_ptr[node], end = row_ptr[node + 1];
  for (; j + 8 <= end; j += 8) {
    int idx[8];
#pragma unroll
    for (int u = 0; u < 8; ++u) idx[u] = col_src[j + u];
    uint2 v[8];
#pragma unroll
    for (int u = 0; u < 8; ++u) v[u] = *(const uint2*)&Tb2[(size_t)idx[u] * 64 + l2 * 2];
#pragma unroll
    for (int u = 0; u < 8; ++u) {
      a0 += bf_lo(v[u].x); a1 += bf_hi(v[u].x);
      a2 += bf_lo(v[u].y); a3 += bf_hi(v[u].y);
    }
  }
  if (j + 4 <= end) {
    int idx[4];
#pragma unroll
    for (int u = 0; u < 4; ++u) idx[u] = col_src[j + u];
    uint2 v[4];
#pragma unroll
    for (int u = 0; u < 4; ++u) v[u] = *(const uint2*)&Tb2[(size_t)idx[u] * 64 + l2 * 2];
#pragma unroll
    for (int u = 0; u < 4; ++u) {
      a0 += bf_lo(v[u].x); a1 += bf_hi(v[u].x);
      a2 += bf_lo(v[u].y); a3 += bf_hi(v[u].y);
    }
    j += 4;
  }
  for (; j < end; ++j) {
    uint2 v = *(const uint2*)&Tb2[(size_t)col_src[j] * 64 + l2 * 2];
    a0 += bf_lo(v.x); a1 += bf_hi(v.x);
    a2 += bf_lo(v.y); a3 += bf_hi(v.y);
  }
  float di = dinv[node];
  float4 bs = *(const float4*)&bias[l2 * 4];
  a0 = fmaxf(di * a0 + bs.x, 0.f);
  a1 = fmaxf(di * a1 + bs.y, 0.f);
  a2 = fmaxf(di * a2 + bs.z, 0.f);
  a3 = fmaxf(di * a3 + bs.w, 0.f);
  uint2 o;
  o.x = (unsigned)f2bf(a0) | ((unsigned)f2bf(a1) << 16);
  o.y = (unsigned)f2bf(a2) | ((unsigned)f2bf(a3) << 16);
  *(uint2*)&Hb[(size_t)node * 64 + l2 * 2] = o;
}

// ---------------- pooling (reads packed bf16 H); 16 nodes per block ----------------

__global__ __launch_bounds__(64) void pool_partial(const unsigned* __restrict__ Hb,
                                                   const int* __restrict__ batch,
                                                   float* __restrict__ pooled, int n) {
  int t = threadIdx.x;  // col pair
  int s = blockIdx.x * 16;
  if (s >= n) return;
  int e = min(s + 16, n);
  int g = batch[s];
  float ax = 0.f, ay = 0.f;
  for (int i = s; i < e; ++i) {
    int bi = batch[i];
    if (bi != g) {
      atomicAdd(&pooled[g * HID + 2 * t], ax);
      atomicAdd(&pooled[g * HID + 2 * t + 1], ay);
      ax = ay = 0.f;
      g = bi;
    }
    unsigned v = Hb[(size_t)i * 64 + t];
    ax += bf_lo(v);
    ay += bf_hi(v);
  }
  atomicAdd(&pooled[g * HID + 2 * t], ax);
  atomicAdd(&pooled[g * HID + 2 * t + 1], ay);
}

__global__ __launch_bounds__(128) void classify_k(const float* __restrict__ pooled,
                                                  const int* __restrict__ batch,
                                                  const float* __restrict__ Wl,
                                                  const float* __restrict__ bl,
                                                  float* __restrict__ out, int n) {
  int g = blockIdx.x;
  int t = threadIdx.x;
  int lo = 0, hi = n;
  while (lo < hi) { int mid = (lo + hi) >> 1; if (batch[mid] < g) lo = mid + 1; else hi = mid; }
  int s = lo;
  hi = n;
  while (lo < hi) { int mid = (lo + hi) >> 1; if (batch[mid] < g + 1) lo = mid + 1; else hi = mid; }
  float c = fmaxf((float)(lo - s), 1.0f);
  __shared__ float p[HID];
  p[t] = pooled[g * HID + t] / c;
  __syncthreads();
  if (t < CLS) {
    float o = bl[t];
    for (int j = 0; j < HID; ++j) o += p[j] * Wl[j * CLS + t];
    out[g * CLS + t] = o;
  }
}

// ---------------- launch ----------------

extern "C" void kernel_launch(void* const* d_in, const int* in_sizes, int n_in,
                              void* d_out, int out_size, void* d_ws, size_t ws_size,
                              hipStream_t stream) {
  const float* x  = (const float*)d_in[0];
  const float* W1 = (const float*)d_in[1];
  const float* b1 = (const float*)d_in[2];
  const float* W2 = (const float*)d_in[3];
  const float* b2 = (const float*)d_in[4];
  const float* W3 = (const float*)d_in[5];
  const float* b3 = (const float*)d_in[6];
  const float* Wl = (const float*)d_in[7];
  const float* bl = (const float*)d_in[8];
  const int* edge_index = (const int*)d_in[9];
  const int* batch = (const int*)d_in[10];

  const int N = in_sizes[10];
  const int E = in_sizes[9] / 2;
  const int G = out_size / CLS;
  const int* src = edge_index;
  const int* dst = edge_index + E;

  uintptr_t p = (uintptr_t)d_ws;
  auto take = [&](size_t bytes) -> void* {
    void* r = (void*)p;
    p += (bytes + 255) & ~(size_t)255;
    return r;
  };
  int*      degi      = (int*)take((size_t)N * 4);
  int*      fillc     = (int*)take((size_t)N * 4);
  int*      row_ptr   = (int*)take((size_t)(N + 1) * 4);
  int*      blockSums = (int*)take(256 * 4);
  float*    dinv      = (float*)take((size_t)N * 4);
  int*      col_src   = (int*)take((size_t)E * 4);
  unsigned short* WtA = (unsigned short*)take((size_t)3 * HID * HID * 2);
  unsigned short* bufTb = (unsigned short*)take((size_t)N * HID * 2);
  unsigned* bufHb     = (unsigned*)take((size_t)N * 64 * 4);
  float*    pooled    = (float*)take((size_t)G * HID * 4);

  int nbN = (N + 255) / 256;
  int nbE = (E + 255) / 256;

  zero_wt<<<nbN + 48, 256, 0, stream>>>(degi, N, nbN, W1, W2, W3, WtA);
  degree_k<<<nbE, 256, 0, stream>>>(dst, degi, E);
  scan_chunk<<<nbN, 256, 0, stream>>>(degi, row_ptr, blockSums, dinv, fillc, pooled, N, G * HID);
  scan_addtop<<<nbN, 256, 0, stream>>>(row_ptr, blockSums, nbN, N, E);
  csr_fill<<<nbE, 256, 0, stream>>>(src, dst, row_ptr, fillc, col_src, E);

  int gemmBlocks = (N + 127) / 128;
  int waves = (N + 1) / 2;
  int aggBlocks = (waves + 3) / 4;  // 4 waves (8 nodes) per 256-thr block

  gemm_mfma<<<gemmBlocks, 256, 0, stream>>>(x, 1, WtA, dinv, bufTb, N);
  aggregate<<<aggBlocks, 256, 0, stream>>>((unsigned*)bufTb, dinv, row_ptr, col_src, b1, bufHb, N);
  gemm_mfma<<<gemmBlocks, 256, 0, stream>>>(bufHb, 0, WtA + (size_t)HID * HID, dinv, bufTb, N);
  aggregate<<<aggBlocks, 256, 0, stream>>>((unsigned*)bufTb, dinv, row_ptr, col_src, b2, bufHb, N);
  gemm_mfma<<<gemmBlocks, 256, 0, stream>>>(bufHb, 0, WtA + (size_t)2 * HID * HID, dinv, bufTb, N);
  aggregate<<<aggBlocks, 256, 0, stream>>>((unsigned*)bufTb, dinv, row_ptr, col_src, b3, bufHb, N);

  pool_partial<<<(N + 15) / 16, 64, 0, stream>>>(bufHb, batch, pooled, N);
  classify_k<<<G, 128, 0, stream>>>(pooled, batch, Wl, bl, (float*)d_out, N);
}